// Round 16
// baseline (416.002 us; speedup 1.0000x reference)
//
#include <hip/hip_runtime.h>
#include <hip/hip_bf16.h>

#define BB 4
#define SS 2048
#define DD 1024
#define HH 16
#define HSZ 64
#define DFF 4096

typedef short short8 __attribute__((ext_vector_type(8)));
typedef float f32x4 __attribute__((ext_vector_type(4)));
typedef unsigned short us4 __attribute__((ext_vector_type(4)));

#define AS1 __attribute__((address_space(1)))
#define AS3 __attribute__((address_space(3)))

__device__ __forceinline__ unsigned short f2bf(float f) {
    return __bfloat16_as_ushort(__float2bfloat16(f));
}
__device__ __forceinline__ float bf2f(unsigned short u) {
    return __uint_as_float(((unsigned int)u) << 16);
}

// ---------------- fused weight repack: all 4 weights, one kernel ----------------
// blocks [0,768): wqkv; [768,1024): proj; [1024,2048): ff1; [2048,3072): ff2
__global__ __launch_bounds__(256) void pack_all_kernel(
    const float* __restrict__ wq, const float* __restrict__ wk,
    const float* __restrict__ wv, const float* __restrict__ proj_w,
    const float* __restrict__ ff1_w, const float* __restrict__ ff2_w,
    __hip_bfloat16* __restrict__ wqkvT, __hip_bfloat16* __restrict__ projT,
    __hip_bfloat16* __restrict__ ff1T, __hip_bfloat16* __restrict__ ff2T)
{
    __shared__ float tile[64][65];
    const int bid = blockIdx.x;
    const int tx = threadIdx.x & 63, ty = threadIdx.x >> 6;

    if (bid < 768) {
        const int kt = bid & 15, hh = (bid >> 4) & 15, sel = bid >> 8;
        const float* src = (sel == 0) ? wq : (sel == 1) ? wk : wv;
        src += (size_t)hh * (DD * HSZ) + (size_t)kt * 64 * HSZ;
        #pragma unroll
        for (int r = 0; r < 64; r += 4)
            tile[r + ty][tx] = src[(size_t)(r + ty) * HSZ + tx];
        __syncthreads();
        unsigned short* o = (unsigned short*)wqkvT + (size_t)(sel * DD + hh * 64) * DD + kt * 64;
        #pragma unroll
        for (int r = 0; r < 64; r += 4) {
            int e = r + ty;
            o[(size_t)e * DD + tx] = f2bf(tile[tx][e]);
        }
        return;
    }
    const float* in; unsigned short* o; int K, N, idx;
    if (bid < 1024)      { in = proj_w; o = (unsigned short*)projT; K = DD;  N = DD;  idx = bid - 768; }
    else if (bid < 2048) { in = ff1_w;  o = (unsigned short*)ff1T;  K = DD;  N = DFF; idx = bid - 1024; }
    else                 { in = ff2_w;  o = (unsigned short*)ff2T;  K = DFF; N = DD;  idx = bid - 2048; }
    const int nb = N >> 6;
    const int tn0 = (idx % nb) << 6, tk0 = (idx / nb) << 6;
    #pragma unroll
    for (int r = 0; r < 64; r += 4)
        tile[r + ty][tx] = in[(size_t)(tk0 + r + ty) * N + tn0 + tx];
    __syncthreads();
    #pragma unroll
    for (int r = 0; r < 64; r += 4) {
        int n = r + ty;
        o[(size_t)(tn0 + n) * K + tk0 + tx] = f2bf(tile[tx][n]);
    }
}

// ---------------- layernorm (input fp32 or bf16) ----------------
template<bool INBF16>
__global__ __launch_bounds__(256) void ln_kernel(
    const void* __restrict__ xin, const float* __restrict__ g,
    const float* __restrict__ b, __hip_bfloat16* __restrict__ out)
{
    int row = blockIdx.x;
    int t = threadIdx.x;
    float4 v;
    if (INBF16) {
        ushort4 u = ((const ushort4*)((const unsigned short*)xin + (size_t)row * DD))[t];
        v = make_float4(bf2f(u.x), bf2f(u.y), bf2f(u.z), bf2f(u.w));
    } else {
        v = ((const float4*)((const float*)xin + (size_t)row * DD))[t];
    }
    float s = v.x + v.y + v.z + v.w;
    float ss = v.x * v.x + v.y * v.y + v.z * v.z + v.w * v.w;
    #pragma unroll
    for (int off = 32; off; off >>= 1) {
        s += __shfl_xor(s, off, 64);
        ss += __shfl_xor(ss, off, 64);
    }
    __shared__ float red[8];
    int w = t >> 6, lane = t & 63;
    if (lane == 0) { red[w] = s; red[4 + w] = ss; }
    __syncthreads();
    s = red[0] + red[1] + red[2] + red[3];
    ss = red[4] + red[5] + red[6] + red[7];
    float mu = s * (1.f / DD);
    float var = ss * (1.f / DD) - mu * mu;
    float rs = rsqrtf(var + 1e-5f);
    float4 gv = ((const float4*)g)[t];
    float4 bv = ((const float4*)b)[t];
    ushort4 pk = make_ushort4(
        f2bf((v.x - mu) * rs * gv.x + bv.x),
        f2bf((v.y - mu) * rs * gv.y + bv.y),
        f2bf((v.z - mu) * rs * gv.z + bv.z),
        f2bf((v.w - mu) * rs * gv.w + bv.w));
    *(ushort4*)((unsigned short*)out + (size_t)row * DD + t * 4) = pk;
}

// ---------------- bf16 MFMA GEMM (round-10 structure; res fp32 or bf16) ----------------
template<int BN, bool BIAS, bool RELU, bool RES, bool OUTF32, bool RESBF16>
__global__ __launch_bounds__(512) void gemm_kernel(
    const __hip_bfloat16* __restrict__ A, const __hip_bfloat16* __restrict__ BT,
    const float* __restrict__ bias, const void* __restrict__ res,
    void* __restrict__ Cout, int M, int N, int K, int nbx)
{
    constexpr int NB = BN / 128;      // B half-buffers
    constexpr int NREP = BN / 64;     // N-frags per wave (4 or 2)
    __shared__ uint4 Ah[2][2][1024];
    __shared__ uint4 Bh[2][NB][1024];

    const int tid = threadIdx.x;
    const int lane = tid & 63;
    const int w = tid >> 6;
    const int lr = lane & 15, g = lane >> 4;
    const int nwg = gridDim.x;
    const int cpx = nwg >> 3;
    const int wg = blockIdx.x;
    const int swz = (wg & 7) * cpx + (wg >> 3);   // XCD-chunked swizzle
    const int bx = swz % nbx, by = swz / nbx;
    const int row0 = by * 256, col0 = bx * BN;
    const int wm = w >> 2, wn = w & 3;
    const int NT = K >> 6;

    f32x4 acc0[4][NREP] = {};
    f32x4 acc1[4][NREP] = {};
    short8 bfr[NREP][2];

    auto stageA = [&](int buf, int half, int t) {
        const int k0 = t * 64;
        #pragma unroll
        for (int j = 0; j < 2; ++j) {
            int s = j * 512 + tid;
            int r = s >> 3;
            int c = (s & 7) ^ (r & 7);
            const __hip_bfloat16* src = A + (size_t)(row0 + half * 128 + r) * K + k0 + c * 8;
            __builtin_amdgcn_global_load_lds((const AS1 void*)src,
                (AS3 void*)(&Ah[buf][half][j * 512 + (tid & ~63)]), 16, 0, 0);
        }
    };
    auto stageB = [&](int buf, int half, int t) {
        const int k0 = t * 64;
        #pragma unroll
        for (int j = 0; j < 2; ++j) {
            int s = j * 512 + tid;
            int r = s >> 3;
            int c = (s & 7) ^ (r & 7);
            const __hip_bfloat16* src = BT + (size_t)(col0 + half * 128 + r) * K + k0 + c * 8;
            __builtin_amdgcn_global_load_lds((const AS1 void*)src,
                (AS3 void*)(&Bh[buf][half][j * 512 + (tid & ~63)]), 16, 0, 0);
        }
    };
    auto loadB = [&](int buf) {
        const int hb = (NB == 2) ? (wn >> 1) : 0;
        const int cb = (NB == 2) ? ((wn & 1) * 64) : (wn * 32);
        #pragma unroll
        for (int n = 0; n < NREP; ++n) {
            int c = cb + n * 16 + lr;
            #pragma unroll
            for (int kk = 0; kk < 2; ++kk)
                bfr[n][kk] = *(const short8*)&Bh[buf][hb][c * 8 + ((kk * 4 + g) ^ (c & 7))];
        }
    };
    auto phase = [&](auto& acc, int buf, int mh) {
        short8 af[4][2];
        #pragma unroll
        for (int mi = 0; mi < 4; ++mi) {
            int r = wm * 64 + mi * 16 + lr;
            #pragma unroll
            for (int kk = 0; kk < 2; ++kk)
                af[mi][kk] = *(const short8*)&Ah[buf][mh][r * 8 + ((kk * 4 + g) ^ (r & 7))];
        }
        asm volatile("s_waitcnt lgkmcnt(0)" ::: "memory");
        __builtin_amdgcn_sched_barrier(0);
        __builtin_amdgcn_s_setprio(1);
        #pragma unroll
        for (int mi = 0; mi < 4; ++mi)
            #pragma unroll
            for (int n = 0; n < NREP; ++n)
                #pragma unroll
                for (int kk = 0; kk < 2; ++kk)
                    acc[mi][n] = __builtin_amdgcn_mfma_f32_16x16x32_bf16(
                        af[mi][kk], bfr[n][kk], acc[mi][n], 0, 0, 0);
        __builtin_amdgcn_s_setprio(0);
    };

    stageA(0, 0, 0);
    stageB(0, 0, 0);
    if constexpr (NB == 2) stageB(0, 1, 0);
    stageA(0, 1, 0);
    stageA(1, 0, 1);
    if constexpr (NB == 2) stageB(1, 0, 1);

    for (int t = 0; t < NT; ++t) {
        const int buf = t & 1;
        if (t < NT - 1) {
            if constexpr (NB == 2) asm volatile("s_waitcnt vmcnt(4)" ::: "memory");
            else                   asm volatile("s_waitcnt vmcnt(2)" ::: "memory");
        } else {
            asm volatile("s_waitcnt vmcnt(0)" ::: "memory");
        }
        __builtin_amdgcn_s_barrier();
        __builtin_amdgcn_sched_barrier(0);
        if (t + 1 < NT) {
            if constexpr (NB == 2) { stageB(buf ^ 1, 1, t + 1); stageA(buf ^ 1, 1, t + 1); }
            else                   { stageB(buf ^ 1, 0, t + 1); stageA(buf ^ 1, 1, t + 1); }
        }
        loadB(buf);
        phase(acc0, buf, 0);
        if (t < NT - 1) {
            if constexpr (NB == 2) asm volatile("s_waitcnt vmcnt(8)" ::: "memory");
            else                   asm volatile("s_waitcnt vmcnt(6)" ::: "memory");
        } else {
            asm volatile("s_waitcnt vmcnt(0)" ::: "memory");
        }
        __builtin_amdgcn_s_barrier();
        __builtin_amdgcn_sched_barrier(0);
        if (t + 2 < NT) {
            stageA(buf, 0, t + 2);
            if constexpr (NB == 2) stageB(buf, 0, t + 2);
        }
        phase(acc1, buf, 1);
    }

    auto store = [&](auto& acc, int mh) {
        #pragma unroll
        for (int mi = 0; mi < 4; ++mi) {
            #pragma unroll
            for (int j = 0; j < 4; ++j) {
                int rr = row0 + mh * 128 + wm * 64 + mi * 16 + g * 4 + j;
                #pragma unroll
                for (int n = 0; n < NREP; ++n) {
                    int cc = col0 + wn * (NREP * 16) + n * 16 + lr;
                    float vv = acc[mi][n][j];
                    if (BIAS) vv += bias[cc];
                    if (RELU) vv = fmaxf(vv, 0.f);
                    if (RES) {
                        if (RESBF16) vv += bf2f(((const unsigned short*)res)[(size_t)rr * N + cc]);
                        else         vv += ((const float*)res)[(size_t)rr * N + cc];
                    }
                    if (OUTF32) ((float*)Cout)[(size_t)rr * N + cc] = vv;
                    else ((__hip_bfloat16*)Cout)[(size_t)rr * N + cc] = __float2bfloat16(vv);
                }
            }
        }
    };
    store(acc0, 0);
    store(acc1, 1);
}

// ---------------- MFMA flash attention: K via global_load_lds ----------------
// K tile slot layout: slot s of row kv holds chunk s^(kv&7) -> linear LDS dest +
// inverse-swizzled per-lane GLOBAL source (both-sides rule satisfied; read side
// unchanged). 2 gl_lds calls x 256 staging threads cover the 8KB tile.
__device__ __forceinline__ void stage_K_async(
    const unsigned short* __restrict__ qkvu, size_t rowbase, int h, int kv0, int tl,
    unsigned short* __restrict__ Kb)
{
    #pragma unroll
    for (int j = 0; j < 2; ++j) {
        int p = j * 256 + tl;              // uint4 slot 0..511
        int kv = p >> 3, ch = p & 7;
        const unsigned short* src = qkvu + rowbase + (size_t)(kv0 + kv) * 3072 + DD
                                    + h * HSZ + ((ch ^ (kv & 7)) * 8);
        __builtin_amdgcn_global_load_lds((const AS1 void*)src,
            (AS3 void*)(Kb + ((size_t)(j * 256 + (tl & ~63)) << 3)), 16, 0, 0);
    }
}

__device__ __forceinline__ void stage_V(
    const unsigned short* __restrict__ qkvu, size_t rowbase, int h, int kv0, int tl,
    unsigned short* __restrict__ Vb)
{
    int bkv = ((tl >> 6) << 2) | (tl & 3);
    int bd = (tl >> 2) & 15;
    const unsigned short* src = qkvu + rowbase + (size_t)(kv0 + bkv * 4) * 3072 + 2 * DD + h * HSZ + bd * 4;
    us4 r0 = *(const us4*)src;
    us4 r1 = *(const us4*)(src + 3072);
    us4 r2 = *(const us4*)(src + 2 * 3072);
    us4 r3 = *(const us4*)(src + 3 * 3072);
    #pragma unroll
    for (int cc = 0; cc < 4; ++cc) {
        int d = bd * 4 + cc;
        us4 wv = { r0[cc], r1[cc], r2[cc], r3[cc] };
        *(us4*)&Vb[d * 64 + (((bkv >> 1) ^ (d & 7)) * 8) + (bkv & 1) * 4] = wv;
    }
}

__device__ __forceinline__ void flash_tile(
    const unsigned short* __restrict__ Kb, const unsigned short* __restrict__ Vb,
    unsigned short* __restrict__ Pw, const short8* qfc, int qgc, int kv0, int q, int g,
    float& m_run, float& l_run, f32x4* oacc, bool masked)
{
    f32x4 st[4] = {};
    __builtin_amdgcn_s_setprio(1);
    #pragma unroll
    for (int tt = 0; tt < 4; ++tt) {
        #pragma unroll
        for (int kk = 0; kk < 2; ++kk) {
            short8 kf = *(const short8*)&Kb[(tt * 16 + q) * 64 + ((4 * kk + g) ^ (q & 7)) * 8];
            st[tt] = __builtin_amdgcn_mfma_f32_16x16x32_bf16(kf, qfc[kk], st[tt], 0, 0, 0);
        }
    }
    __builtin_amdgcn_s_setprio(0);

    const float SC = 0.1803368801111731f;   // 0.125 * log2(e): log2-domain scores
    float mt = -1e30f;
    if (masked) {
        #pragma unroll
        for (int tt = 0; tt < 4; ++tt)
            #pragma unroll
            for (int j = 0; j < 4; ++j) {
                float s = st[tt][j] * SC;
                int kvg = kv0 + tt * 16 + g * 4 + j;
                s = (kvg <= qgc) ? s : -1e30f;
                st[tt][j] = s;
                mt = fmaxf(mt, s);
            }
    } else {
        #pragma unroll
        for (int tt = 0; tt < 4; ++tt)
            #pragma unroll
            for (int j = 0; j < 4; ++j) {
                float s = st[tt][j] * SC;
                st[tt][j] = s;
                mt = fmaxf(mt, s);
            }
    }
    mt = fmaxf(mt, __shfl_xor(mt, 16, 64));
    mt = fmaxf(mt, __shfl_xor(mt, 32, 64));

    bool defer = __all(mt <= m_run + 11.0f);
    if (!defer) {
        float m_new = fmaxf(m_run, mt);
        float corr = exp2f(m_run - m_new);
        #pragma unroll
        for (int j = 0; j < 4; ++j) {
            float cj = __shfl(corr, g * 4 + j, 64);
            #pragma unroll
            for (int dn = 0; dn < 4; ++dn)
                oacc[dn][j] *= cj;
        }
        l_run *= corr;
        m_run = m_new;
    }

    float lsum = 0.f;
    #pragma unroll
    for (int tt = 0; tt < 4; ++tt)
        #pragma unroll
        for (int j = 0; j < 4; ++j) {
            float p = exp2f(st[tt][j] - m_run);
            st[tt][j] = p;
            lsum += p;
        }
    lsum += __shfl_xor(lsum, 16, 64);
    lsum += __shfl_xor(lsum, 32, 64);
    l_run += lsum;

    __builtin_amdgcn_s_setprio(1);
    #pragma unroll
    for (int kk = 0; kk < 2; ++kk) {
        #pragma unroll
        for (int rt = 0; rt < 2; ++rt) {
            int tt = kk * 2 + rt;
            unsigned int lo = ((unsigned int)f2bf(st[tt][1]) << 16) | (unsigned int)f2bf(st[tt][0]);
            unsigned int hi = ((unsigned int)f2bf(st[tt][3]) << 16) | (unsigned int)f2bf(st[tt][2]);
            uint2 pk = make_uint2(lo, hi);
            *(uint2*)&Pw[q * 32 + ((2 * rt + (g >> 1)) ^ ((q >> 1) & 3)) * 8 + (g & 1) * 4] = pk;
        }
        short8 pf = *(const short8*)&Pw[q * 32 + (g ^ ((q >> 1) & 3)) * 8];
        #pragma unroll
        for (int dn = 0; dn < 4; ++dn) {
            short8 vf = *(const short8*)&Vb[(dn * 16 + q) * 64 + ((4 * kk + g) ^ (q & 7)) * 8];
            oacc[dn] = __builtin_amdgcn_mfma_f32_16x16x32_bf16(pf, vf, oacc[dn], 0, 0, 0);
        }
    }
    __builtin_amdgcn_s_setprio(0);
}

__global__ __launch_bounds__(512, 4) void attn_kernel(
    const __hip_bfloat16* __restrict__ qkv, __hip_bfloat16* __restrict__ o)
{
    __shared__ unsigned short K_lds[2][64 * 64];    // 16KB
    __shared__ unsigned short Vt_lds[2][64 * 64];   // 16KB
    __shared__ unsigned short P_lds[8 * 512];       // 8KB  -> total 40KB, 4 blk/CU

    const int t = threadIdx.x;
    const int lane = t & 63, w = t >> 6;
    const int grp = w >> 2, wq4 = w & 3, tl = t & 255;
    const int q = lane & 15, g = lane >> 4;
    // XCD-chunked swizzle: same-(b,h) pq-blocks share K/V via one XCD's L2.
    const int wg = blockIdx.x;
    const int swzb = (wg & 7) * 128 + (wg >> 3);
    const int pq = swzb & 15;
    const int h = (swzb >> 4) & 15;
    const int b = swzb >> 8;
    const int qtA = pq, qtB = 31 - pq;
    const int qt1 = grp ? qtB : qtA;
    const unsigned short* qkvu = (const unsigned short*)qkv;
    const size_t rowbase = (size_t)(b * SS) * 3072;
    unsigned short* Kb = K_lds[grp];
    unsigned short* Vb = Vt_lds[grp];
    unsigned short* Pw = &P_lds[w * 512];
    unsigned short* op = (unsigned short*)o;

    int qt_cur = qt1;
    int qgc = qt_cur * 64 + wq4 * 16 + q;
    short8 qfc[2];
    #pragma unroll
    for (int kk = 0; kk < 2; ++kk)
        qfc[kk] = *(const short8*)(qkvu + rowbase + (size_t)qgc * 3072 + h * HSZ + kk * 32 + g * 8);

    f32x4 oacc[4] = {};
    float m_run = -1e30f, l_run = 0.f;

    // ---- loop1: tiles 0..pq, SAME kv for both groups: grp0 K (async), grp1 V ----
    for (int it = 0; it <= pq; ++it) {
        __syncthreads();
        if (grp == 0) stage_K_async(qkvu, rowbase, h, it * 64, tl, K_lds[0]);
        else          stage_V(qkvu, rowbase, h, it * 64, tl, Vt_lds[0]);
        __syncthreads();
        flash_tile(K_lds[0], Vt_lds[0], Pw, qfc, qgc, it * 64, q, g, m_run, l_run, oacc,
                   it == qt_cur);
    }

    // ---- group0: write tile-pq output, switch to helping with tile qtB ----
    if (grp == 0) {
        #pragma unroll
        for (int j = 0; j < 4; ++j) {
            float lj = __shfl(l_run, g * 4 + j, 64);
            float inv = 1.f / lj;
            int orow = qtA * 64 + wq4 * 16 + g * 4 + j;
            #pragma unroll
            for (int dn = 0; dn < 4; ++dn)
                op[(size_t)(b * SS + orow) * DD + h * HSZ + dn * 16 + q] = f2bf(oacc[dn][j] * inv);
        }
        qt_cur = qtB;
        qgc = qtB * 64 + wq4 * 16 + q;
        #pragma unroll
        for (int kk = 0; kk < 2; ++kk)
            qfc[kk] = *(const short8*)(qkvu + rowbase + (size_t)qgc * 3072 + h * HSZ + kk * 32 + g * 8);
        m_run = -1e30f; l_run = 0.f;
        #pragma unroll
        for (int dn = 0; dn < 4; ++dn) oacc[dn] = f32x4{0.f, 0.f, 0.f, 0.f};
    }

    // ---- loop2: disjoint tiles per group -> per-group staging into buffer[grp] ----
    for (int it2 = 0; it2 < 16 - pq; ++it2) {
        int tile = grp ? (pq + 1 + it2) : (16 + it2);
        bool active = grp ? (tile <= 15) : true;
        __syncthreads();
        if (active) {
            stage_K_async(qkvu, rowbase, h, tile * 64, tl, Kb);
            stage_V(qkvu, rowbase, h, tile * 64, tl, Vb);
        }
        __syncthreads();
        if (active) flash_tile(Kb, Vb, Pw, qfc, qgc, tile * 64, q, g, m_run, l_run, oacc,
                               tile == qt_cur);
    }

    // ---- merge partial states for tile qtB ----
    __syncthreads();
    float* obuf = (float*)K_lds;     // 16KB: 4 waves x 1024 floats
    float* mlbuf = (float*)P_lds;    // 4 waves x 32 floats
    if (grp == 0) {
        #pragma unroll
        for (int dn = 0; dn < 4; ++dn)
            #pragma unroll
            for (int j = 0; j < 4; ++j)
                obuf[wq4 * 1024 + lane * 16 + dn * 4 + j] = oacc[dn][j];
        if (g == 0) { mlbuf[wq4 * 32 + q] = m_run; mlbuf[wq4 * 32 + 16 + q] = l_run; }
    }
    __syncthreads();
    if (grp == 1) {
        float mA = mlbuf[wq4 * 32 + q];
        float lA = mlbuf[wq4 * 32 + 16 + q];
        float mM = fmaxf(m_run, mA);
        float sB = exp2f(m_run - mM);
        float sA = exp2f(mA - mM);
        float lM = l_run * sB + lA * sA;
        #pragma unroll
        for (int j = 0; j < 4; ++j) {
            float sBj = __shfl(sB, g * 4 + j, 64);
            float sAj = __shfl(sA, g * 4 + j, 64);
            float lMj = __shfl(lM, g * 4 + j, 64);
            float inv = 1.f / lMj;
            int orow = qtB * 64 + wq4 * 16 + g * 4 + j;
            #pragma unroll
            for (int dn = 0; dn < 4; ++dn) {
                float oA = obuf[wq4 * 1024 + lane * 16 + dn * 4 + j];
                float vv = (oacc[dn][j] * sBj + oA * sAj) * inv;
                op[(size_t)(b * SS + orow) * DD + h * HSZ + dn * 16 + q] = f2bf(vv);
            }
        }
    }
}

// ---------------- launch ----------------
extern "C" void kernel_launch(void* const* d_in, const int* in_sizes, int n_in,
                              void* d_out, int out_size, void* d_ws, size_t ws_size,
                              hipStream_t stream)
{
    const float* x      = (const float*)d_in[0];
    const float* wq     = (const float*)d_in[1];
    const float* wk     = (const float*)d_in[2];
    const float* wv     = (const float*)d_in[3];
    const float* proj_w = (const float*)d_in[4];
    const float* proj_b = (const float*)d_in[5];
    const float* ff1_w  = (const float*)d_in[6];
    const float* ff1_b  = (const float*)d_in[7];
    const float* ff2_w  = (const float*)d_in[8];
    const float* ff2_b  = (const float*)d_in[9];
    const float* ln1_g  = (const float*)d_in[10];
    const float* ln1_b  = (const float*)d_in[11];
    const float* ln2_g  = (const float*)d_in[12];
    const float* ln2_b  = (const float*)d_in[13];
    float* out = (float*)d_out;

    char* ws = (char*)d_ws;
    const size_t MB = 1ull << 20;
    __hip_bfloat16* h     = (__hip_bfloat16*)(ws);              // 16MB (h / h2)
    __hip_bfloat16* qkv   = (__hip_bfloat16*)(ws + 16 * MB);    // 48MB
    __hip_bfloat16* obuf  = (__hip_bfloat16*)(ws + 64 * MB);    // 16MB
    __hip_bfloat16* x1b   = (__hip_bfloat16*)(ws + 80 * MB);    // 16MB (bf16 residual)
    __hip_bfloat16* wqkvT = (__hip_bfloat16*)(ws + 112 * MB);   // 6MB
    __hip_bfloat16* projT = (__hip_bfloat16*)(ws + 118 * MB);   // 2MB
    __hip_bfloat16* ff1T  = (__hip_bfloat16*)(ws + 120 * MB);   // 8MB
    __hip_bfloat16* ff2T  = (__hip_bfloat16*)(ws + 128 * MB);   // 8MB
    __hip_bfloat16* f1    = (__hip_bfloat16*)(ws + 16 * MB);    // 64MB, aliases qkv+obuf (dead by then)

    const int ROWS = BB * SS;   // 8192

    pack_all_kernel<<<3072, 256, 0, stream>>>(wq, wk, wv, proj_w, ff1_w, ff2_w,
                                              wqkvT, projT, ff1T, ff2T);

    ln_kernel<false><<<ROWS, 256, 0, stream>>>(x, ln1_g, ln1_b, h);
    gemm_kernel<128, false, false, false, false, false><<<(ROWS / 256) * (3 * DD / 128), 512, 0, stream>>>(
        h, wqkvT, nullptr, nullptr, qkv, ROWS, 3 * DD, DD, 3 * DD / 128);
    attn_kernel<<<BB * HH * 16, 512, 0, stream>>>(qkv, obuf);
    // x1b (bf16) = x + obuf @ proj_w + proj_b
    gemm_kernel<128, true, false, true, false, false><<<(ROWS / 256) * (DD / 128), 512, 0, stream>>>(
        obuf, projT, proj_b, x, x1b, ROWS, DD, DD, DD / 128);
    ln_kernel<true><<<ROWS, 256, 0, stream>>>(x1b, ln2_g, ln2_b, h);
    gemm_kernel<256, true, true, false, false, false><<<(ROWS / 256) * (DFF / 256), 512, 0, stream>>>(
        h, ff1T, ff1_b, nullptr, f1, ROWS, DFF, DD, DFF / 256);
    // out (fp32) = x1b + f1 @ ff2_w + ff2_b
    gemm_kernel<128, true, false, true, true, true><<<(ROWS / 256) * (DD / 128), 512, 0, stream>>>(
        f1, ff2T, ff2_b, x1b, out, ROWS, DD, DFF, DD / 128);
}

// Round 17
// 403.536 us; speedup vs baseline: 1.0309x; 1.0309x over previous
//
#include <hip/hip_runtime.h>
#include <hip/hip_bf16.h>

#define BB 4
#define SS 2048
#define DD 1024
#define HH 16
#define HSZ 64
#define DFF 4096

typedef short short8 __attribute__((ext_vector_type(8)));
typedef float f32x4 __attribute__((ext_vector_type(4)));
typedef unsigned short us4 __attribute__((ext_vector_type(4)));

#define AS1 __attribute__((address_space(1)))
#define AS3 __attribute__((address_space(3)))

__device__ __forceinline__ unsigned short f2bf(float f) {
    return __bfloat16_as_ushort(__float2bfloat16(f));
}
__device__ __forceinline__ float bf2f(unsigned short u) {
    return __uint_as_float(((unsigned int)u) << 16);
}

// ---------------- fused weight repack: all 4 weights, one kernel ----------------
__global__ __launch_bounds__(256) void pack_all_kernel(
    const float* __restrict__ wq, const float* __restrict__ wk,
    const float* __restrict__ wv, const float* __restrict__ proj_w,
    const float* __restrict__ ff1_w, const float* __restrict__ ff2_w,
    __hip_bfloat16* __restrict__ wqkvT, __hip_bfloat16* __restrict__ projT,
    __hip_bfloat16* __restrict__ ff1T, __hip_bfloat16* __restrict__ ff2T)
{
    __shared__ float tile[64][65];
    const int bid = blockIdx.x;
    const int tx = threadIdx.x & 63, ty = threadIdx.x >> 6;

    if (bid < 768) {
        const int kt = bid & 15, hh = (bid >> 4) & 15, sel = bid >> 8;
        const float* src = (sel == 0) ? wq : (sel == 1) ? wk : wv;
        src += (size_t)hh * (DD * HSZ) + (size_t)kt * 64 * HSZ;
        #pragma unroll
        for (int r = 0; r < 64; r += 4)
            tile[r + ty][tx] = src[(size_t)(r + ty) * HSZ + tx];
        __syncthreads();
        unsigned short* o = (unsigned short*)wqkvT + (size_t)(sel * DD + hh * 64) * DD + kt * 64;
        #pragma unroll
        for (int r = 0; r < 64; r += 4) {
            int e = r + ty;
            o[(size_t)e * DD + tx] = f2bf(tile[tx][e]);
        }
        return;
    }
    const float* in; unsigned short* o; int K, N, idx;
    if (bid < 1024)      { in = proj_w; o = (unsigned short*)projT; K = DD;  N = DD;  idx = bid - 768; }
    else if (bid < 2048) { in = ff1_w;  o = (unsigned short*)ff1T;  K = DD;  N = DFF; idx = bid - 1024; }
    else                 { in = ff2_w;  o = (unsigned short*)ff2T;  K = DFF; N = DD;  idx = bid - 2048; }
    const int nb = N >> 6;
    const int tn0 = (idx % nb) << 6, tk0 = (idx / nb) << 6;
    #pragma unroll
    for (int r = 0; r < 64; r += 4)
        tile[r + ty][tx] = in[(size_t)(tk0 + r + ty) * N + tn0 + tx];
    __syncthreads();
    #pragma unroll
    for (int r = 0; r < 64; r += 4) {
        int n = r + ty;
        o[(size_t)(tn0 + n) * K + tk0 + tx] = f2bf(tile[tx][n]);
    }
}

// ---------------- layernorm (input fp32 or bf16) ----------------
template<bool INBF16>
__global__ __launch_bounds__(256) void ln_kernel(
    const void* __restrict__ xin, const float* __restrict__ g,
    const float* __restrict__ b, __hip_bfloat16* __restrict__ out)
{
    int row = blockIdx.x;
    int t = threadIdx.x;
    float4 v;
    if (INBF16) {
        ushort4 u = ((const ushort4*)((const unsigned short*)xin + (size_t)row * DD))[t];
        v = make_float4(bf2f(u.x), bf2f(u.y), bf2f(u.z), bf2f(u.w));
    } else {
        v = ((const float4*)((const float*)xin + (size_t)row * DD))[t];
    }
    float s = v.x + v.y + v.z + v.w;
    float ss = v.x * v.x + v.y * v.y + v.z * v.z + v.w * v.w;
    #pragma unroll
    for (int off = 32; off; off >>= 1) {
        s += __shfl_xor(s, off, 64);
        ss += __shfl_xor(ss, off, 64);
    }
    __shared__ float red[8];
    int w = t >> 6, lane = t & 63;
    if (lane == 0) { red[w] = s; red[4 + w] = ss; }
    __syncthreads();
    s = red[0] + red[1] + red[2] + red[3];
    ss = red[4] + red[5] + red[6] + red[7];
    float mu = s * (1.f / DD);
    float var = ss * (1.f / DD) - mu * mu;
    float rs = rsqrtf(var + 1e-5f);
    float4 gv = ((const float4*)g)[t];
    float4 bv = ((const float4*)b)[t];
    ushort4 pk = make_ushort4(
        f2bf((v.x - mu) * rs * gv.x + bv.x),
        f2bf((v.y - mu) * rs * gv.y + bv.y),
        f2bf((v.z - mu) * rs * gv.z + bv.z),
        f2bf((v.w - mu) * rs * gv.w + bv.w));
    *(ushort4*)((unsigned short*)out + (size_t)row * DD + t * 4) = pk;
}

// ---------------- bf16 MFMA GEMM (round-10 structure; res fp32 or bf16) ----------------
template<int BN, bool BIAS, bool RELU, bool RES, bool OUTF32, bool RESBF16>
__global__ __launch_bounds__(512) void gemm_kernel(
    const __hip_bfloat16* __restrict__ A, const __hip_bfloat16* __restrict__ BT,
    const float* __restrict__ bias, const void* __restrict__ res,
    void* __restrict__ Cout, int M, int N, int K, int nbx)
{
    constexpr int NB = BN / 128;      // B half-buffers
    constexpr int NREP = BN / 64;     // N-frags per wave (4 or 2)
    __shared__ uint4 Ah[2][2][1024];
    __shared__ uint4 Bh[2][NB][1024];

    const int tid = threadIdx.x;
    const int lane = tid & 63;
    const int w = tid >> 6;
    const int lr = lane & 15, g = lane >> 4;
    const int nwg = gridDim.x;
    const int cpx = nwg >> 3;
    const int wg = blockIdx.x;
    const int swz = (wg & 7) * cpx + (wg >> 3);   // XCD-chunked swizzle
    const int bx = swz % nbx, by = swz / nbx;
    const int row0 = by * 256, col0 = bx * BN;
    const int wm = w >> 2, wn = w & 3;
    const int NT = K >> 6;

    f32x4 acc0[4][NREP] = {};
    f32x4 acc1[4][NREP] = {};
    short8 bfr[NREP][2];

    auto stageA = [&](int buf, int half, int t) {
        const int k0 = t * 64;
        #pragma unroll
        for (int j = 0; j < 2; ++j) {
            int s = j * 512 + tid;
            int r = s >> 3;
            int c = (s & 7) ^ (r & 7);
            const __hip_bfloat16* src = A + (size_t)(row0 + half * 128 + r) * K + k0 + c * 8;
            __builtin_amdgcn_global_load_lds((const AS1 void*)src,
                (AS3 void*)(&Ah[buf][half][j * 512 + (tid & ~63)]), 16, 0, 0);
        }
    };
    auto stageB = [&](int buf, int half, int t) {
        const int k0 = t * 64;
        #pragma unroll
        for (int j = 0; j < 2; ++j) {
            int s = j * 512 + tid;
            int r = s >> 3;
            int c = (s & 7) ^ (r & 7);
            const __hip_bfloat16* src = BT + (size_t)(col0 + half * 128 + r) * K + k0 + c * 8;
            __builtin_amdgcn_global_load_lds((const AS1 void*)src,
                (AS3 void*)(&Bh[buf][half][j * 512 + (tid & ~63)]), 16, 0, 0);
        }
    };
    auto loadB = [&](int buf) {
        const int hb = (NB == 2) ? (wn >> 1) : 0;
        const int cb = (NB == 2) ? ((wn & 1) * 64) : (wn * 32);
        #pragma unroll
        for (int n = 0; n < NREP; ++n) {
            int c = cb + n * 16 + lr;
            #pragma unroll
            for (int kk = 0; kk < 2; ++kk)
                bfr[n][kk] = *(const short8*)&Bh[buf][hb][c * 8 + ((kk * 4 + g) ^ (c & 7))];
        }
    };
    auto phase = [&](auto& acc, int buf, int mh) {
        short8 af[4][2];
        #pragma unroll
        for (int mi = 0; mi < 4; ++mi) {
            int r = wm * 64 + mi * 16 + lr;
            #pragma unroll
            for (int kk = 0; kk < 2; ++kk)
                af[mi][kk] = *(const short8*)&Ah[buf][mh][r * 8 + ((kk * 4 + g) ^ (r & 7))];
        }
        asm volatile("s_waitcnt lgkmcnt(0)" ::: "memory");
        __builtin_amdgcn_sched_barrier(0);
        __builtin_amdgcn_s_setprio(1);
        #pragma unroll
        for (int mi = 0; mi < 4; ++mi)
            #pragma unroll
            for (int n = 0; n < NREP; ++n)
                #pragma unroll
                for (int kk = 0; kk < 2; ++kk)
                    acc[mi][n] = __builtin_amdgcn_mfma_f32_16x16x32_bf16(
                        af[mi][kk], bfr[n][kk], acc[mi][n], 0, 0, 0);
        __builtin_amdgcn_s_setprio(0);
    };

    stageA(0, 0, 0);
    stageB(0, 0, 0);
    if constexpr (NB == 2) stageB(0, 1, 0);
    stageA(0, 1, 0);
    stageA(1, 0, 1);
    if constexpr (NB == 2) stageB(1, 0, 1);

    for (int t = 0; t < NT; ++t) {
        const int buf = t & 1;
        if (t < NT - 1) {
            if constexpr (NB == 2) asm volatile("s_waitcnt vmcnt(4)" ::: "memory");
            else                   asm volatile("s_waitcnt vmcnt(2)" ::: "memory");
        } else {
            asm volatile("s_waitcnt vmcnt(0)" ::: "memory");
        }
        __builtin_amdgcn_s_barrier();
        __builtin_amdgcn_sched_barrier(0);
        if (t + 1 < NT) {
            if constexpr (NB == 2) { stageB(buf ^ 1, 1, t + 1); stageA(buf ^ 1, 1, t + 1); }
            else                   { stageB(buf ^ 1, 0, t + 1); stageA(buf ^ 1, 1, t + 1); }
        }
        loadB(buf);
        phase(acc0, buf, 0);
        if (t < NT - 1) {
            if constexpr (NB == 2) asm volatile("s_waitcnt vmcnt(8)" ::: "memory");
            else                   asm volatile("s_waitcnt vmcnt(6)" ::: "memory");
        } else {
            asm volatile("s_waitcnt vmcnt(0)" ::: "memory");
        }
        __builtin_amdgcn_s_barrier();
        __builtin_amdgcn_sched_barrier(0);
        if (t + 2 < NT) {
            stageA(buf, 0, t + 2);
            if constexpr (NB == 2) stageB(buf, 0, t + 2);
        }
        phase(acc1, buf, 1);
    }

    auto store = [&](auto& acc, int mh) {
        #pragma unroll
        for (int mi = 0; mi < 4; ++mi) {
            #pragma unroll
            for (int j = 0; j < 4; ++j) {
                int rr = row0 + mh * 128 + wm * 64 + mi * 16 + g * 4 + j;
                #pragma unroll
                for (int n = 0; n < NREP; ++n) {
                    int cc = col0 + wn * (NREP * 16) + n * 16 + lr;
                    float vv = acc[mi][n][j];
                    if (BIAS) vv += bias[cc];
                    if (RELU) vv = fmaxf(vv, 0.f);
                    if (RES) {
                        if (RESBF16) vv += bf2f(((const unsigned short*)res)[(size_t)rr * N + cc]);
                        else         vv += ((const float*)res)[(size_t)rr * N + cc];
                    }
                    if (OUTF32) ((float*)Cout)[(size_t)rr * N + cc] = vv;
                    else ((__hip_bfloat16*)Cout)[(size_t)rr * N + cc] = __float2bfloat16(vv);
                }
            }
        }
    };
    store(acc0, 0);
    store(acc1, 1);
}

// ---------------- MFMA flash attention: paired kv tiles (128 kv per barrier window) ----------------
__device__ __forceinline__ void stage_K(
    const unsigned short* __restrict__ qkvu, size_t rowbase, int h, int kv0, int tl,
    unsigned short* __restrict__ Kb)
{
    int kv = tl >> 2, c = tl & 3;
    const unsigned short* src = qkvu + rowbase + (size_t)(kv0 + kv) * 3072 + DD + h * HSZ + c * 16;
    uint4 v0 = *(const uint4*)src;
    uint4 v1 = *(const uint4*)(src + 8);
    int sw = kv & 7;
    *(uint4*)&Kb[kv * 64 + ((2 * c) ^ sw) * 8] = v0;
    *(uint4*)&Kb[kv * 64 + ((2 * c + 1) ^ sw) * 8] = v1;
}

__device__ __forceinline__ void stage_V(
    const unsigned short* __restrict__ qkvu, size_t rowbase, int h, int kv0, int tl,
    unsigned short* __restrict__ Vb)
{
    int bkv = ((tl >> 6) << 2) | (tl & 3);
    int bd = (tl >> 2) & 15;
    const unsigned short* src = qkvu + rowbase + (size_t)(kv0 + bkv * 4) * 3072 + 2 * DD + h * HSZ + bd * 4;
    us4 r0 = *(const us4*)src;
    us4 r1 = *(const us4*)(src + 3072);
    us4 r2 = *(const us4*)(src + 2 * 3072);
    us4 r3 = *(const us4*)(src + 3 * 3072);
    #pragma unroll
    for (int cc = 0; cc < 4; ++cc) {
        int d = bd * 4 + cc;
        us4 wv = { r0[cc], r1[cc], r2[cc], r3[cc] };
        *(us4*)&Vb[d * 64 + (((bkv >> 1) ^ (d & 7)) * 8) + (bkv & 1) * 4] = wv;
    }
}

__device__ __forceinline__ void flash_tile(
    const unsigned short* __restrict__ Kb, const unsigned short* __restrict__ Vb,
    unsigned short* __restrict__ Pw, const short8* qfc, int qgc, int kv0, int q, int g,
    float& m_run, float& l_run, f32x4* oacc, bool masked)
{
    f32x4 st[4] = {};
    __builtin_amdgcn_s_setprio(1);
    #pragma unroll
    for (int tt = 0; tt < 4; ++tt) {
        #pragma unroll
        for (int kk = 0; kk < 2; ++kk) {
            short8 kf = *(const short8*)&Kb[(tt * 16 + q) * 64 + ((4 * kk + g) ^ (q & 7)) * 8];
            st[tt] = __builtin_amdgcn_mfma_f32_16x16x32_bf16(kf, qfc[kk], st[tt], 0, 0, 0);
        }
    }
    __builtin_amdgcn_s_setprio(0);

    const float SC = 0.1803368801111731f;   // 0.125 * log2(e): log2-domain scores
    float mt = -1e30f;
    if (masked) {
        #pragma unroll
        for (int tt = 0; tt < 4; ++tt)
            #pragma unroll
            for (int j = 0; j < 4; ++j) {
                float s = st[tt][j] * SC;
                int kvg = kv0 + tt * 16 + g * 4 + j;
                s = (kvg <= qgc) ? s : -1e30f;
                st[tt][j] = s;
                mt = fmaxf(mt, s);
            }
    } else {
        #pragma unroll
        for (int tt = 0; tt < 4; ++tt)
            #pragma unroll
            for (int j = 0; j < 4; ++j) {
                float s = st[tt][j] * SC;
                st[tt][j] = s;
                mt = fmaxf(mt, s);
            }
    }
    mt = fmaxf(mt, __shfl_xor(mt, 16, 64));
    mt = fmaxf(mt, __shfl_xor(mt, 32, 64));

    bool defer = __all(mt <= m_run + 11.0f);
    if (!defer) {
        float m_new = fmaxf(m_run, mt);
        float corr = exp2f(m_run - m_new);
        #pragma unroll
        for (int j = 0; j < 4; ++j) {
            float cj = __shfl(corr, g * 4 + j, 64);
            #pragma unroll
            for (int dn = 0; dn < 4; ++dn)
                oacc[dn][j] *= cj;
        }
        l_run *= corr;
        m_run = m_new;
    }

    float lsum = 0.f;
    #pragma unroll
    for (int tt = 0; tt < 4; ++tt)
        #pragma unroll
        for (int j = 0; j < 4; ++j) {
            float p = exp2f(st[tt][j] - m_run);
            st[tt][j] = p;
            lsum += p;
        }
    lsum += __shfl_xor(lsum, 16, 64);
    lsum += __shfl_xor(lsum, 32, 64);
    l_run += lsum;

    __builtin_amdgcn_s_setprio(1);
    #pragma unroll
    for (int kk = 0; kk < 2; ++kk) {
        #pragma unroll
        for (int rt = 0; rt < 2; ++rt) {
            int tt = kk * 2 + rt;
            unsigned int lo = ((unsigned int)f2bf(st[tt][1]) << 16) | (unsigned int)f2bf(st[tt][0]);
            unsigned int hi = ((unsigned int)f2bf(st[tt][3]) << 16) | (unsigned int)f2bf(st[tt][2]);
            uint2 pk = make_uint2(lo, hi);
            *(uint2*)&Pw[q * 32 + ((2 * rt + (g >> 1)) ^ ((q >> 1) & 3)) * 8 + (g & 1) * 4] = pk;
        }
        short8 pf = *(const short8*)&Pw[q * 32 + (g ^ ((q >> 1) & 3)) * 8];
        #pragma unroll
        for (int dn = 0; dn < 4; ++dn) {
            short8 vf = *(const short8*)&Vb[(dn * 16 + q) * 64 + ((4 * kk + g) ^ (q & 7)) * 8];
            oacc[dn] = __builtin_amdgcn_mfma_f32_16x16x32_bf16(pf, vf, oacc[dn], 0, 0, 0);
        }
    }
    __builtin_amdgcn_s_setprio(0);
}

__global__ __launch_bounds__(512, 4) void attn_kernel(
    const __hip_bfloat16* __restrict__ qkv, __hip_bfloat16* __restrict__ o)
{
    __shared__ unsigned short K_lds[2][2][64 * 64];   // [grp][pair-half] 32KB
    __shared__ unsigned short Vt_lds[2][2][64 * 64];  // 32KB
    __shared__ unsigned short P_lds[8 * 512];         // 8KB -> 72KB total

    const int t = threadIdx.x;
    const int lane = t & 63, w = t >> 6;
    const int grp = w >> 2, wq4 = w & 3, tl = t & 255;
    const int q = lane & 15, g = lane >> 4;
    // XCD-chunked swizzle: same-(b,h) pq-blocks share K/V via one XCD's L2.
    const int wg = blockIdx.x;
    const int swzb = (wg & 7) * 128 + (wg >> 3);
    const int pq = swzb & 15;
    const int h = (swzb >> 4) & 15;
    const int b = swzb >> 8;
    const int qtA = pq, qtB = 31 - pq;
    const int qt1 = grp ? qtB : qtA;
    const unsigned short* qkvu = (const unsigned short*)qkv;
    const size_t rowbase = (size_t)(b * SS) * 3072;
    unsigned short* Pw = &P_lds[w * 512];
    unsigned short* op = (unsigned short*)o;

    int qt_cur = qt1;
    int qgc = qt_cur * 64 + wq4 * 16 + q;
    short8 qfc[2];
    #pragma unroll
    for (int kk = 0; kk < 2; ++kk)
        qfc[kk] = *(const short8*)(qkvu + rowbase + (size_t)qgc * 3072 + h * HSZ + kk * 32 + g * 8);

    f32x4 oacc[4] = {};
    float m_run = -1e30f, l_run = 0.f;

    // ---- loop1: paired tiles (2p, 2p+1), SAME kv for both groups; grp0->K, grp1->V ----
    const int P1 = (pq >> 1) + 1;
    for (int p = 0; p < P1; ++p) {
        const int t0 = 2 * p, t1 = 2 * p + 1;
        __syncthreads();
        if (grp == 0) {
            stage_K(qkvu, rowbase, h, t0 * 64, tl, K_lds[0][0]);
            stage_K(qkvu, rowbase, h, t1 * 64, tl, K_lds[0][1]);
        } else {
            stage_V(qkvu, rowbase, h, t0 * 64, tl, Vt_lds[0][0]);
            stage_V(qkvu, rowbase, h, t1 * 64, tl, Vt_lds[0][1]);
        }
        __syncthreads();
        flash_tile(K_lds[0][0], Vt_lds[0][0], Pw, qfc, qgc, t0 * 64, q, g, m_run, l_run, oacc,
                   t0 >= qt_cur);
        flash_tile(K_lds[0][1], Vt_lds[0][1], Pw, qfc, qgc, t1 * 64, q, g, m_run, l_run, oacc,
                   t1 >= qt_cur);
    }

    // ---- group0: write tile-pq output, switch to helping with tile qtB ----
    if (grp == 0) {
        #pragma unroll
        for (int j = 0; j < 4; ++j) {
            float lj = __shfl(l_run, g * 4 + j, 64);
            float inv = 1.f / lj;
            int orow = qtA * 64 + wq4 * 16 + g * 4 + j;
            #pragma unroll
            for (int dn = 0; dn < 4; ++dn)
                op[(size_t)(b * SS + orow) * DD + h * HSZ + dn * 16 + q] = f2bf(oacc[dn][j] * inv);
        }
        qt_cur = qtB;
        qgc = qtB * 64 + wq4 * 16 + q;
        #pragma unroll
        for (int kk = 0; kk < 2; ++kk)
            qfc[kk] = *(const short8*)(qkvu + rowbase + (size_t)qgc * 3072 + h * HSZ + kk * 32 + g * 8);
        m_run = -1e30f; l_run = 0.f;
        #pragma unroll
        for (int dn = 0; dn < 4; ++dn) oacc[dn] = f32x4{0.f, 0.f, 0.f, 0.f};
    }

    // ---- loop2: disjoint paired tiles per group; each group stages its own K+V ----
    // grp0: tiles 16+2*it2, +1 (for q-tile qtB; tiles > qtB auto-zero via mask)
    // grp1: tiles s1+2*it2, +1 where s1 = (pq|1)+1; active only while tile <= 15
    const int P2 = 8 - (pq >> 1);
    const int s1 = (pq | 1) + 1;
    for (int it2 = 0; it2 < P2; ++it2) {
        const int t0 = grp ? (s1 + 2 * it2) : (16 + 2 * it2);
        const int t1 = t0 + 1;
        const bool a0 = grp ? (t0 <= 15) : (t0 <= qtB);
        const bool a1 = grp ? (t1 <= 15) : (t1 <= qtB);
        __syncthreads();
        if (a0) {
            stage_K(qkvu, rowbase, h, t0 * 64, tl, K_lds[grp][0]);
            stage_V(qkvu, rowbase, h, t0 * 64, tl, Vt_lds[grp][0]);
        }
        if (a1) {
            stage_K(qkvu, rowbase, h, t1 * 64, tl, K_lds[grp][1]);
            stage_V(qkvu, rowbase, h, t1 * 64, tl, Vt_lds[grp][1]);
        }
        __syncthreads();
        if (a0) flash_tile(K_lds[grp][0], Vt_lds[grp][0], Pw, qfc, qgc, t0 * 64, q, g,
                           m_run, l_run, oacc, t0 >= qt_cur);
        if (a1) flash_tile(K_lds[grp][1], Vt_lds[grp][1], Pw, qfc, qgc, t1 * 64, q, g,
                           m_run, l_run, oacc, t1 >= qt_cur);
    }

    // ---- merge partial states for tile qtB ----
    __syncthreads();
    float* obuf = (float*)K_lds;     // 16KB scratch: 4 waves x 1024 floats
    float* mlbuf = (float*)P_lds;    // 4 waves x 32 floats
    if (grp == 0) {
        #pragma unroll
        for (int dn = 0; dn < 4; ++dn)
            #pragma unroll
            for (int j = 0; j < 4; ++j)
                obuf[wq4 * 1024 + lane * 16 + dn * 4 + j] = oacc[dn][j];
        if (g == 0) { mlbuf[wq4 * 32 + q] = m_run; mlbuf[wq4 * 32 + 16 + q] = l_run; }
    }
    __syncthreads();
    if (grp == 1) {
        float mA = mlbuf[wq4 * 32 + q];
        float lA = mlbuf[wq4 * 32 + 16 + q];
        float mM = fmaxf(m_run, mA);
        float sB = exp2f(m_run - mM);
        float sA = exp2f(mA - mM);
        float lM = l_run * sB + lA * sA;
        #pragma unroll
        for (int j = 0; j < 4; ++j) {
            float sBj = __shfl(sB, g * 4 + j, 64);
            float sAj = __shfl(sA, g * 4 + j, 64);
            float lMj = __shfl(lM, g * 4 + j, 64);
            float inv = 1.f / lMj;
            int orow = qtB * 64 + wq4 * 16 + g * 4 + j;
            #pragma unroll
            for (int dn = 0; dn < 4; ++dn) {
                float oA = obuf[wq4 * 1024 + lane * 16 + dn * 4 + j];
                float vv = (oacc[dn][j] * sBj + oA * sAj) * inv;
                op[(size_t)(b * SS + orow) * DD + h * HSZ + dn * 16 + q] = f2bf(vv);
            }
        }
    }
}

// ---------------- launch ----------------
extern "C" void kernel_launch(void* const* d_in, const int* in_sizes, int n_in,
                              void* d_out, int out_size, void* d_ws, size_t ws_size,
                              hipStream_t stream)
{
    const float* x      = (const float*)d_in[0];
    const float* wq     = (const float*)d_in[1];
    const float* wk     = (const float*)d_in[2];
    const float* wv     = (const float*)d_in[3];
    const float* proj_w = (const float*)d_in[4];
    const float* proj_b = (const float*)d_in[5];
    const float* ff1_w  = (const float*)d_in[6];
    const float* ff1_b  = (const float*)d_in[7];
    const float* ff2_w  = (const float*)d_in[8];
    const float* ff2_b  = (const float*)d_in[9];
    const float* ln1_g  = (const float*)d_in[10];
    const float* ln1_b  = (const float*)d_in[11];
    const float* ln2_g  = (const float*)d_in[12];
    const float* ln2_b  = (const float*)d_in[13];
    float* out = (float*)d_out;

    char* ws = (char*)d_ws;
    const size_t MB = 1ull << 20;
    __hip_bfloat16* h     = (__hip_bfloat16*)(ws);              // 16MB (h / h2)
    __hip_bfloat16* qkv   = (__hip_bfloat16*)(ws + 16 * MB);    // 48MB
    __hip_bfloat16* obuf  = (__hip_bfloat16*)(ws + 64 * MB);    // 16MB
    __hip_bfloat16* x1b   = (__hip_bfloat16*)(ws + 80 * MB);    // 16MB (bf16 residual)
    __hip_bfloat16* wqkvT = (__hip_bfloat16*)(ws + 112 * MB);   // 6MB
    __hip_bfloat16* projT = (__hip_bfloat16*)(ws + 118 * MB);   // 2MB
    __hip_bfloat16* ff1T  = (__hip_bfloat16*)(ws + 120 * MB);   // 8MB
    __hip_bfloat16* ff2T  = (__hip_bfloat16*)(ws + 128 * MB);   // 8MB
    __hip_bfloat16* f1    = (__hip_bfloat16*)(ws + 16 * MB);    // 64MB, aliases qkv+obuf (dead by then)

    const int ROWS = BB * SS;   // 8192

    pack_all_kernel<<<3072, 256, 0, stream>>>(wq, wk, wv, proj_w, ff1_w, ff2_w,
                                              wqkvT, projT, ff1T, ff2T);

    ln_kernel<false><<<ROWS, 256, 0, stream>>>(x, ln1_g, ln1_b, h);
    gemm_kernel<128, false, false, false, false, false><<<(ROWS / 256) * (3 * DD / 128), 512, 0, stream>>>(
        h, wqkvT, nullptr, nullptr, qkv, ROWS, 3 * DD, DD, 3 * DD / 128);
    attn_kernel<<<BB * HH * 16, 512, 0, stream>>>(qkv, obuf);
    gemm_kernel<128, true, false, true, false, false><<<(ROWS / 256) * (DD / 128), 512, 0, stream>>>(
        obuf, projT, proj_b, x, x1b, ROWS, DD, DD, DD / 128);
    ln_kernel<true><<<ROWS, 256, 0, stream>>>(x1b, ln2_g, ln2_b, h);
    gemm_kernel<256, true, true, false, false, false><<<(ROWS / 256) * (DFF / 256), 512, 0, stream>>>(
        h, ff1T, ff1_b, nullptr, f1, ROWS, DFF, DD, DFF / 256);
    gemm_kernel<128, true, false, true, true, true><<<(ROWS / 256) * (DD / 128), 512, 0, stream>>>(
        f1, ff2T, ff2_b, x1b, out, ROWS, DD, DFF, DD / 128);
}